// Round 24
// baseline (55.102 us; speedup 1.0000x reference)
//
#include <hip/hip_runtime.h>
#include <math.h>

#define BB 8
#define TT 2048
#define CC 1024
#define HH 64
constexpr float SC2 = 0.03125f * 1.4426950408889634f; // (1/sqrt(1024)) * log2(e)

typedef __attribute__((ext_vector_type(8))) short bf16x8;
typedef __attribute__((ext_vector_type(8))) short s16x8;
typedef __attribute__((ext_vector_type(4))) short s16x4;
typedef __attribute__((ext_vector_type(4))) float f32x4;

static __device__ __forceinline__ short f2bf(float f) {
    union { float f; unsigned u; } un; un.f = f;
    unsigned r = un.u + 0x7FFFu + ((un.u >> 16) & 1u); // RNE
    return (short)(r >> 16);
}
static __device__ __forceinline__ float bf2f(short h) {
    union { unsigned u; float f; } un; un.u = ((unsigned)(unsigned short)h) << 16;
    return un.f;
}
static __device__ __forceinline__ bf16x8 cat8(s16x4 lo, s16x4 hi) {
    return __builtin_shufflevector(lo, hi, 0, 1, 2, 3, 4, 5, 6, 7);
}

// ---------------- Kernel 1: fused qkv projection, fp32 W direct (wconv folded in) ----------------
// 512 blocks x 32 rows, 2 blocks/CU, 2-deep prefetch, dbuf LDS.
__global__ __launch_bounds__(256) void proj_fused(
    const float* __restrict__ x,
    const float* __restrict__ Wk, const float* __restrict__ Wq, const float* __restrict__ Wv,
    short* __restrict__ ko, short* __restrict__ qo, short* __restrict__ vT)
{
    __shared__ short At[2][32][72];
    __shared__ short Bt[2][192][72];

    const int tid  = threadIdx.x;
    const int row0 = blockIdx.x * 32;
    const int wv = tid >> 6, lane = tid & 63;
    const int lr = lane & 15, lg = lane >> 4;

    const int ar  = tid >> 4;            // A rows: ar, ar+16
    const int ac4 = (tid & 15) * 4;
    const int br_ = tid >> 3;            // B rows: br_ + 32*it
    const int bc8 = (tid & 7) * 8;

    f32x4 acc[2][3] = {};
    float4 axA0, axA1, axB0, axB1;
    float4 bwA[6][2], bwB[6][2];         // W fp32 staged in regs (8 floats per it)

#define PL(AX0, AX1, BW, k0_) do {                                                     \
    AX0 = *reinterpret_cast<const float4*>(&x[(size_t)(row0 + ar) * CC + (k0_) + ac4]);       \
    AX1 = *reinterpret_cast<const float4*>(&x[(size_t)(row0 + ar + 16) * CC + (k0_) + ac4]);  \
    _Pragma("unroll")                                                                  \
    for (int it = 0; it < 6; ++it) {                                                   \
        const float* Wsel = (it < 2) ? Wk : (it < 4) ? Wq : Wv;                        \
        const int wrow = br_ + 32 * (it & 1);                                          \
        BW[it][0] = *reinterpret_cast<const float4*>(&Wsel[(size_t)wrow * CC + (k0_) + bc8]);     \
        BW[it][1] = *reinterpret_cast<const float4*>(&Wsel[(size_t)wrow * CC + (k0_) + bc8 + 4]); \
    }                                                                                  \
  } while (0)

#define PW(bf_, AX0, AX1, BW) do {                                                     \
    s16x4 h0 = { f2bf(AX0.x), f2bf(AX0.y), f2bf(AX0.z), f2bf(AX0.w) };                 \
    s16x4 h1 = { f2bf(AX1.x), f2bf(AX1.y), f2bf(AX1.z), f2bf(AX1.w) };                 \
    *reinterpret_cast<s16x4*>(&At[bf_][ar][ac4]) = h0;                                 \
    *reinterpret_cast<s16x4*>(&At[bf_][ar + 16][ac4]) = h1;                            \
    _Pragma("unroll")                                                                  \
    for (int it = 0; it < 6; ++it) {                                                   \
        s16x8 hw = { f2bf(BW[it][0].x), f2bf(BW[it][0].y), f2bf(BW[it][0].z), f2bf(BW[it][0].w), \
                     f2bf(BW[it][1].x), f2bf(BW[it][1].y), f2bf(BW[it][1].z), f2bf(BW[it][1].w) };\
        *reinterpret_cast<s16x8*>(&Bt[bf_][br_ + 32 * it][bc8]) = hw;                  \
    }                                                                                  \
  } while (0)

#define PCOMP(bf_) do {                                                                \
    _Pragma("unroll")                                                                  \
    for (int kk = 0; kk < 64; kk += 32) {                                              \
        bf16x8 aF[2], bF[3];                                                           \
        _Pragma("unroll")                                                              \
        for (int m = 0; m < 2; ++m) {                                                  \
            const int row_ = m * 16 + lr;                                              \
            aF[m] = cat8(*reinterpret_cast<const s16x4*>(&At[bf_][row_][kk + 4 * lg]), \
                         *reinterpret_cast<const s16x4*>(&At[bf_][row_][kk + 16 + 4 * lg])); \
        }                                                                              \
        _Pragma("unroll")                                                              \
        for (int n = 0; n < 3; ++n) {                                                  \
            const int brow_ = wv * 48 + n * 16 + lr;                                   \
            bF[n] = cat8(*reinterpret_cast<const s16x4*>(&Bt[bf_][brow_][kk + 4 * lg]),\
                         *reinterpret_cast<const s16x4*>(&Bt[bf_][brow_][kk + 16 + 4 * lg])); \
        }                                                                              \
        _Pragma("unroll")                                                              \
        for (int m = 0; m < 2; ++m)                                                    \
            _Pragma("unroll")                                                          \
            for (int n = 0; n < 3; ++n)                                                \
                acc[m][n] = __builtin_amdgcn_mfma_f32_16x16x32_bf16(aF[m], bF[n], acc[m][n], 0, 0, 0); \
    }                                                                                  \
  } while (0)

    PL(axA0, axA1, bwA, 0);      // tile 0
    PL(axB0, axB1, bwB, 64);     // tile 1
    PW(0, axA0, axA1, bwA);      // LDS buf0 <- tile 0
    __syncthreads();

#pragma unroll
    for (int ks = 0; ks < 16; ks += 2) {
        if (ks + 2 < 16) PL(axA0, axA1, bwA, (ks + 2) * 64);
        PCOMP(0);
        PW(1, axB0, axB1, bwB);
        __syncthreads();
        if (ks + 3 < 16) PL(axB0, axB1, bwB, (ks + 3) * 64);
        PCOMP(1);
        if (ks + 2 < 16) PW(0, axA0, axA1, bwA);
        __syncthreads();
    }
#undef PL
#undef PW
#undef PCOMP

    const int bb = row0 >> 11;
    const int t0 = row0 & 2047;
#pragma unroll
    for (int m = 0; m < 2; ++m)
#pragma unroll
        for (int n = 0; n < 3; ++n) {
            const int col0 = wv * 48 + n * 16;
            const int mat  = col0 >> 6;
            const int hcol = (col0 & 63) + lr;
            const int trow = m * 16 + 4 * lg;
            if (mat == 2) {
                s16x4 pk = { f2bf(acc[m][n][0]), f2bf(acc[m][n][1]),
                             f2bf(acc[m][n][2]), f2bf(acc[m][n][3]) };
                *reinterpret_cast<s16x4*>(&vT[((size_t)bb * HH + hcol) * TT + t0 + trow]) = pk;
            } else {
                short* o = (mat == 0) ? ko : qo;
#pragma unroll
                for (int j = 0; j < 4; ++j)
                    o[(size_t)(row0 + trow + j) * HH + hcol] = f2bf(acc[m][n][j]);
            }
        }
}

// ---------------- Kernel 2: causal flash attention, parity-4 + XCD b-locality + defer-max + T5 ----------------
__global__ __launch_bounds__(256) void attn_split(
    const short* __restrict__ q, const short* __restrict__ k,
    const short* __restrict__ vT, short* __restrict__ opb16,
    float* __restrict__ mm, float* __restrict__ ll)
{
    __shared__ short kl[2][4096];  // [kv][h] swizzled
    __shared__ short vl[2][4096];  // [h][t]  swizzled

    const int tid = threadIdx.x;
    const int w = tid >> 6, lane = tid & 63;
    const int lr = lane & 15, lg = lane >> 4;

    const int idx = blockIdx.x;
    const int b = idx & 7;          // XCD-locality: one batch per XCD
    const int j = idx >> 3;         // 0..127 within XCD chunk
    int jq, s;
    if (j < 64) { jq = j >> 2;              s = j & 3; }
    else        { jq = 31 - ((j - 64) >> 2); s = j & 3; }
    const int cnt = (jq >= s) ? ((jq - s) >> 2) + 1 : 0;

    const short* qb = q  + ((size_t)b * TT + jq * 64 + w * 16) * HH;
    const short* kb = k  + (size_t)b * TT * HH;   // [t][h]
    const short* vb = vT + (size_t)b * HH * TT;   // [h][t]

    bf16x8 aQ[2];
#pragma unroll
    for (int k2 = 0; k2 < 2; ++k2)
        aQ[k2] = cat8(*reinterpret_cast<const s16x4*>(&qb[lr * HH + k2 * 32 + 4 * lg]),
                      *reinterpret_cast<const s16x4*>(&qb[lr * HH + k2 * 32 + 16 + 4 * lg]));

    const int r0 = w * 16 + (lane >> 3);
    const int r1 = r0 + 8;
    const int c7 = lane & 7;
    const int swc = (c7 * 8) ^ ((r0 & 7) << 3);

    f32x4 o[4] = {};
    float m2 = -INFINITY, l_run = 0.f;

    s16x8 sk0, sk1, sv0, sv1;

#define LOADG(t_) do {                                                       \
    const short* kt_ = kb + (size_t)(t_) * 64 * HH;                          \
    const short* vt_ = vb + (t_) * 64;                                       \
    sk0 = *reinterpret_cast<const s16x8*>(&kt_[r0 * HH + c7 * 8]);           \
    sk1 = *reinterpret_cast<const s16x8*>(&kt_[r1 * HH + c7 * 8]);           \
    sv0 = *reinterpret_cast<const s16x8*>(&vt_[(size_t)r0 * TT + c7 * 8]);   \
    sv1 = *reinterpret_cast<const s16x8*>(&vt_[(size_t)r1 * TT + c7 * 8]);   \
  } while (0)

#define WRITELDS(bf_) do {                                                   \
    *reinterpret_cast<s16x8*>(&kl[bf_][r0 * 64 + swc]) = sk0;                \
    *reinterpret_cast<s16x8*>(&kl[bf_][r1 * 64 + swc]) = sk1;                \
    *reinterpret_cast<s16x8*>(&vl[bf_][r0 * 64 + swc]) = sv0;                \
    *reinterpret_cast<s16x8*>(&vl[bf_][r1 * 64 + swc]) = sv1;                \
  } while (0)

    if (cnt > 0) {
        LOADG(s);
        WRITELDS(0);
        __syncthreads();

        for (int u = 0; u < cnt; ++u) {
            const int cur = u & 1;
            const int jt = s + 4 * u;
            if (u + 1 < cnt) LOADG(jt + 4);

            // ---- S^T = K Q^T ----
            f32x4 sv[4] = {};
            __builtin_amdgcn_s_setprio(1);
#pragma unroll
            for (int k2 = 0; k2 < 2; ++k2)
#pragma unroll
                for (int n = 0; n < 4; ++n) {
                    const int row = n * 16 + lr;
                    const int sw = (row & 7) << 3;
                    s16x4 klo = *reinterpret_cast<const s16x4*>(&kl[cur][row * 64 + ((32 * k2 + 4 * lg) ^ sw)]);
                    s16x4 khi = *reinterpret_cast<const s16x4*>(&kl[cur][row * 64 + ((32 * k2 + 4 * lg + 16) ^ sw)]);
                    sv[n] = __builtin_amdgcn_mfma_f32_16x16x32_bf16(cat8(klo, khi), aQ[k2], sv[n], 0, 0, 0);
                }
            __builtin_amdgcn_s_setprio(0);

            if (jt == jq) { // diag tile
#pragma unroll
                for (int n = 0; n < 4; ++n)
#pragma unroll
                    for (int jj = 0; jj < 4; ++jj)
                        if (n * 16 + 4 * lg + jj > w * 16 + lr) sv[n][jj] = -3.0e38f;
            }

            float tm = fmaxf(fmaxf(fmaxf(sv[0][0], sv[0][1]), fmaxf(sv[0][2], sv[0][3])),
                             fmaxf(fmaxf(sv[1][0], sv[1][1]), fmaxf(sv[1][2], sv[1][3])));
            tm = fmaxf(tm, fmaxf(fmaxf(fmaxf(sv[2][0], sv[2][1]), fmaxf(sv[2][2], sv[2][3])),
                                 fmaxf(fmaxf(sv[3][0], sv[3][1]), fmaxf(sv[3][2], sv[3][3]))));
            tm = fmaxf(tm, __shfl_xor(tm, 16));
            tm = fmaxf(tm, __shfl_xor(tm, 32));

            // T13 defer-max
            if (!__all((tm * SC2 - m2) <= 8.f)) {
                const float mnew = fmaxf(m2, tm * SC2);
                const float alpha = exp2f(m2 - mnew);
                m2 = mnew;
                l_run *= alpha;
                float alj[4];
#pragma unroll
                for (int jj = 0; jj < 4; ++jj) alj[jj] = __shfl(alpha, 4 * lg + jj);
#pragma unroll
                for (int n = 0; n < 4; ++n)
#pragma unroll
                    for (int jj = 0; jj < 4; ++jj)
                        o[n][jj] *= alj[jj];
            }

            float psum = 0.f;
#pragma unroll
            for (int n = 0; n < 4; ++n)
#pragma unroll
                for (int jj = 0; jj < 4; ++jj) {
                    float p = exp2f(fmaf(sv[n][jj], SC2, -m2));
                    sv[n][jj] = p;
                    psum += p;
                }
            psum += __shfl_xor(psum, 16);
            psum += __shfl_xor(psum, 32);
            l_run += psum;

            bf16x8 aP[2];
#pragma unroll
            for (int k2 = 0; k2 < 2; ++k2) {
                bf16x8 tt;
#pragma unroll
                for (int jj = 0; jj < 4; ++jj) {
                    tt[jj]     = f2bf(sv[2 * k2][jj]);
                    tt[4 + jj] = f2bf(sv[2 * k2 + 1][jj]);
                }
                aP[k2] = tt;
            }
            __builtin_amdgcn_s_setprio(1);
#pragma unroll
            for (int k2 = 0; k2 < 2; ++k2)
#pragma unroll
                for (int n = 0; n < 4; ++n) {
                    const int row = n * 16 + lr;
                    const int sw = (row & 7) << 3;
                    s16x4 vlo = *reinterpret_cast<const s16x4*>(&vl[cur][row * 64 + ((32 * k2 + 4 * lg) ^ sw)]);
                    s16x4 vhi = *reinterpret_cast<const s16x4*>(&vl[cur][row * 64 + ((32 * k2 + 4 * lg + 16) ^ sw)]);
                    o[n] = __builtin_amdgcn_mfma_f32_16x16x32_bf16(aP[k2], cat8(vlo, vhi), o[n], 0, 0, 0);
                }
            __builtin_amdgcn_s_setprio(0);

            if (u + 1 < cnt) WRITELDS(cur ^ 1);
            __syncthreads();
        }
    }
#undef LOADG
#undef WRITELDS

    // ---- write UNNORMALIZED bf16 partials ----
    short* opb = opb16 + (((size_t)s * BB + b) * TT + jq * 64 + w * 16) * HH;
#pragma unroll
    for (int n = 0; n < 4; ++n)
#pragma unroll
        for (int jj = 0; jj < 4; ++jj)
            opb[(size_t)(4 * lg + jj) * HH + n * 16 + lr] = f2bf(o[n][jj]);
    if (lg == 0) {
        const size_t mi = ((size_t)s * BB + b) * TT + jq * 64 + w * 16 + lr;
        mm[mi] = m2;
        ll[mi] = l_run;
    }
}

// ---------------- Kernel 3: merge the four kv-parity partials (bf16 in, fp32 out) ----------------
__global__ __launch_bounds__(256) void attn_merge4(
    const short* __restrict__ opb16, const float* __restrict__ mm,
    const float* __restrict__ ll, float* __restrict__ out)
{
    const int t = blockIdx.x * 256 + threadIdx.x; // 65536
    const int row = t >> 2;                       // b*TT + trow
    const int seg = (t & 3) * 16;
    const size_t BT = (size_t)BB * TT;

    float mw[4], lw[4];
#pragma unroll
    for (int w = 0; w < 4; ++w) { mw[w] = mm[w * BT + row]; lw[w] = ll[w * BT + row]; }
    const float M = fmaxf(fmaxf(mw[0], mw[1]), fmaxf(mw[2], mw[3]));
    float ew[4], L = 0.f;
#pragma unroll
    for (int w = 0; w < 4; ++w) { ew[w] = exp2f(mw[w] - M); L += ew[w] * lw[w]; }
    const float inv = 1.f / L;

    float accv[16];
#pragma unroll
    for (int u = 0; u < 16; ++u) accv[u] = 0.f;
#pragma unroll
    for (int w = 0; w < 4; ++w) {
        const short* pb = opb16 + ((w * BT + row) * HH + seg);
        s16x8 v0 = *reinterpret_cast<const s16x8*>(pb);
        s16x8 v1 = *reinterpret_cast<const s16x8*>(pb + 8);
#pragma unroll
        for (int u = 0; u < 8; ++u) {
            accv[u]     += ew[w] * bf2f(v0[u]);
            accv[8 + u] += ew[w] * bf2f(v1[u]);
        }
    }
    float* po = out + (size_t)row * HH + seg;
#pragma unroll
    for (int u = 0; u < 4; ++u) {
        float4 rr = { accv[4 * u] * inv, accv[4 * u + 1] * inv,
                      accv[4 * u + 2] * inv, accv[4 * u + 3] * inv };
        *reinterpret_cast<float4*>(po + 4 * u) = rr;
    }
}

extern "C" void kernel_launch(void* const* d_in, const int* in_sizes, int n_in,
                              void* d_out, int out_size, void* d_ws, size_t ws_size,
                              hipStream_t stream) {
    const float* x  = (const float*)d_in[0];
    const float* Wk = (const float*)d_in[1];
    const float* Wq = (const float*)d_in[2];
    const float* Wv = (const float*)d_in[3];
    float* outp = (float*)d_out;

    const size_t n = (size_t)BB * TT * HH; // 1,048,576
    short* kbuf  = (short*)d_ws;
    short* qbuf  = kbuf + n;
    short* vbuf  = qbuf + n;                // vT layout [B][H][T]
    short* opb16 = vbuf + n;                // [4][B][T][H] bf16 partials (8 MB)
    float* mm    = (float*)(opb16 + 4 * n); // [4][B][T]
    float* ll    = mm + 4 * BB * TT;

    proj_fused<<<512, 256, 0, stream>>>(x, Wk, Wq, Wv, kbuf, qbuf, vbuf);
    attn_split<<<1024, 256, 0, stream>>>(qbuf, kbuf, vbuf, opb16, mm, ll);
    attn_merge4<<<256, 256, 0, stream>>>(opb16, mm, ll, outp);
}

// Round 25
// 54.864 us; speedup vs baseline: 1.0043x; 1.0043x over previous
//
#include <hip/hip_runtime.h>
#include <math.h>

#define BB 8
#define TT 2048
#define CC 1024
#define HH 64
constexpr float SC2 = 0.03125f * 1.4426950408889634f; // (1/sqrt(1024)) * log2(e)

typedef __attribute__((ext_vector_type(8))) short bf16x8;
typedef __attribute__((ext_vector_type(8))) short s16x8;
typedef __attribute__((ext_vector_type(4))) short s16x4;
typedef __attribute__((ext_vector_type(4))) float f32x4;

static __device__ __forceinline__ short f2bf(float f) {
    union { float f; unsigned u; } un; un.f = f;
    unsigned r = un.u + 0x7FFFu + ((un.u >> 16) & 1u); // RNE
    return (short)(r >> 16);
}
static __device__ __forceinline__ float bf2f(short h) {
    union { unsigned u; float f; } un; un.u = ((unsigned)(unsigned short)h) << 16;
    return un.f;
}
static __device__ __forceinline__ bf16x8 cat8(s16x4 lo, s16x4 hi) {
    return __builtin_shufflevector(lo, hi, 0, 1, 2, 3, 4, 5, 6, 7);
}

// ---------------- Kernel 0: W fp32 -> bf16 (concatenated [192][1024]) ----------------
__global__ __launch_bounds__(256) void wconv(
    const float* __restrict__ Wk, const float* __restrict__ Wq, const float* __restrict__ Wv,
    short* __restrict__ wbf)
{
    const int i = blockIdx.x * 256 + threadIdx.x;
    const int elem = i * 4;
    const int mat = elem >> 16;
    const int off = elem & 65535;
    const float* W = (mat == 0) ? Wk : (mat == 1) ? Wq : Wv;
    float4 w4 = *reinterpret_cast<const float4*>(&W[off]);
    s16x4 h = { f2bf(w4.x), f2bf(w4.y), f2bf(w4.z), f2bf(w4.w) };
    *reinterpret_cast<s16x4*>(&wbf[elem]) = h;
}

// ---------------- Kernel 1: qkv projection, BM=64 x BN=96, 3 blocks/CU ----------------
// 512 blocks (row-tile rb = idx>>1, n-half nh = idx&1) x 256 thr. 45KB LDS -> 3 blocks/CU:
// three independent blocks overlap each other's per-step barrier drains (the measured
// r24 bottleneck: vmcnt(0)-at-barrier serializes a lone block's K-loop).
__global__ __launch_bounds__(256) void proj_fused(
    const float* __restrict__ x, const short* __restrict__ wbf,
    short* __restrict__ ko, short* __restrict__ qo, short* __restrict__ vT)
{
    __shared__ short At[2][64][72];   // 18KB
    __shared__ short Bt[2][96][72];   // 27KB

    const int tid  = threadIdx.x;
    const int rb   = blockIdx.x >> 1;
    const int nh   = blockIdx.x & 1;      // n-half: cols [96*nh, 96*nh+96)
    const int row0 = rb * 64;
    const int wv = tid >> 6, lane = tid & 63;
    const int wm = wv >> 1, wn = wv & 1;  // 32-row half x 48-col half
    const int lr = lane & 15, lg = lane >> 4;

    const int ar  = tid >> 4;             // A staging: rows idx>>4, 4 iters
    const int ac4 = (tid & 15) * 4;
    const int br_ = tid >> 3;             // B staging: rows br_+32*it, 3 iters
    const int bc8 = (tid & 7) * 8;
    const short* wb = wbf + (size_t)nh * 96 * CC;

    f32x4 acc[2][3] = {};
    float4 axA[4], axB[4];
    s16x8 bwA[3], bwB[3];

#define PL(AX, BW, k0_) do {                                                           \
    _Pragma("unroll")                                                                  \
    for (int it = 0; it < 4; ++it) {                                                   \
        int idx_ = tid + 256 * it;                                                     \
        AX[it] = *reinterpret_cast<const float4*>(                                     \
            &x[(size_t)(row0 + (idx_ >> 4)) * CC + (k0_) + (idx_ & 15) * 4]);          \
    }                                                                                  \
    _Pragma("unroll")                                                                  \
    for (int it = 0; it < 3; ++it)                                                     \
        BW[it] = *reinterpret_cast<const s16x8*>(&wb[(size_t)(br_ + 32 * it) * CC + (k0_) + bc8]); \
  } while (0)

#define PW(bf_, AX, BW) do {                                                           \
    _Pragma("unroll")                                                                  \
    for (int it = 0; it < 4; ++it) {                                                   \
        int idx_ = tid + 256 * it;                                                     \
        s16x4 h_ = { f2bf(AX[it].x), f2bf(AX[it].y), f2bf(AX[it].z), f2bf(AX[it].w) }; \
        *reinterpret_cast<s16x4*>(&At[bf_][idx_ >> 4][(idx_ & 15) * 4]) = h_;          \
    }                                                                                  \
    _Pragma("unroll")                                                                  \
    for (int it = 0; it < 3; ++it)                                                     \
        *reinterpret_cast<s16x8*>(&Bt[bf_][br_ + 32 * it][bc8]) = BW[it];              \
  } while (0)

#define PCOMP(bf_) do {                                                                \
    _Pragma("unroll")                                                                  \
    for (int kk = 0; kk < 64; kk += 32) {                                              \
        bf16x8 aF[2], bF[3];                                                           \
        _Pragma("unroll")                                                              \
        for (int m = 0; m < 2; ++m) {                                                  \
            const int row_ = wm * 32 + m * 16 + lr;                                    \
            aF[m] = cat8(*reinterpret_cast<const s16x4*>(&At[bf_][row_][kk + 4 * lg]), \
                         *reinterpret_cast<const s16x4*>(&At[bf_][row_][kk + 16 + 4 * lg])); \
        }                                                                              \
        _Pragma("unroll")                                                              \
        for (int n = 0; n < 3; ++n) {                                                  \
            const int brow_ = wn * 48 + n * 16 + lr;                                   \
            bF[n] = cat8(*reinterpret_cast<const s16x4*>(&Bt[bf_][brow_][kk + 4 * lg]),\
                         *reinterpret_cast<const s16x4*>(&Bt[bf_][brow_][kk + 16 + 4 * lg])); \
        }                                                                              \
        _Pragma("unroll")                                                              \
        for (int m = 0; m < 2; ++m)                                                    \
            _Pragma("unroll")                                                          \
            for (int n = 0; n < 3; ++n)                                                \
                acc[m][n] = __builtin_amdgcn_mfma_f32_16x16x32_bf16(aF[m], bF[n], acc[m][n], 0, 0, 0); \
    }                                                                                  \
  } while (0)

    PL(axA, bwA, 0);
    PL(axB, bwB, 64);
    PW(0, axA, bwA);
    __syncthreads();

#pragma unroll
    for (int ks = 0; ks < 16; ks += 2) {
        if (ks + 2 < 16) PL(axA, bwA, (ks + 2) * 64);
        PCOMP(0);
        PW(1, axB, bwB);
        __syncthreads();
        if (ks + 3 < 16) PL(axB, bwB, (ks + 3) * 64);
        PCOMP(1);
        if (ks + 2 < 16) PW(0, axA, bwA);
        __syncthreads();
    }
#undef PL
#undef PW
#undef PCOMP

    const int bb = row0 >> 11;
    const int t0 = row0 & 2047;
#pragma unroll
    for (int m = 0; m < 2; ++m)
#pragma unroll
        for (int n = 0; n < 3; ++n) {
            const int col0 = nh * 96 + wn * 48 + n * 16;  // 16-aligned, single matrix
            const int mat  = col0 >> 6;
            const int hcol = (col0 & 63) + lr;
            const int trow = wm * 32 + m * 16 + 4 * lg;
            if (mat == 2) {
                s16x4 pk = { f2bf(acc[m][n][0]), f2bf(acc[m][n][1]),
                             f2bf(acc[m][n][2]), f2bf(acc[m][n][3]) };
                *reinterpret_cast<s16x4*>(&vT[((size_t)bb * HH + hcol) * TT + t0 + trow]) = pk;
            } else {
                short* o = (mat == 0) ? ko : qo;
#pragma unroll
                for (int j = 0; j < 4; ++j)
                    o[(size_t)(row0 + trow + j) * HH + hcol] = f2bf(acc[m][n][j]);
            }
        }
}

// ---------------- Kernel 2: causal flash attention, parity-4 + XCD b-locality + defer-max + T5 ----------------
__global__ __launch_bounds__(256) void attn_split(
    const short* __restrict__ q, const short* __restrict__ k,
    const short* __restrict__ vT, short* __restrict__ opb16,
    float* __restrict__ mm, float* __restrict__ ll)
{
    __shared__ short kl[2][4096];  // [kv][h] swizzled
    __shared__ short vl[2][4096];  // [h][t]  swizzled

    const int tid = threadIdx.x;
    const int w = tid >> 6, lane = tid & 63;
    const int lr = lane & 15, lg = lane >> 4;

    const int idx = blockIdx.x;
    const int b = idx & 7;          // XCD-locality: one batch per XCD
    const int j = idx >> 3;
    int jq, s;
    if (j < 64) { jq = j >> 2;              s = j & 3; }
    else        { jq = 31 - ((j - 64) >> 2); s = j & 3; }
    const int cnt = (jq >= s) ? ((jq - s) >> 2) + 1 : 0;

    const short* qb = q  + ((size_t)b * TT + jq * 64 + w * 16) * HH;
    const short* kb = k  + (size_t)b * TT * HH;   // [t][h]
    const short* vb = vT + (size_t)b * HH * TT;   // [h][t]

    bf16x8 aQ[2];
#pragma unroll
    for (int k2 = 0; k2 < 2; ++k2)
        aQ[k2] = cat8(*reinterpret_cast<const s16x4*>(&qb[lr * HH + k2 * 32 + 4 * lg]),
                      *reinterpret_cast<const s16x4*>(&qb[lr * HH + k2 * 32 + 16 + 4 * lg]));

    const int r0 = w * 16 + (lane >> 3);
    const int r1 = r0 + 8;
    const int c7 = lane & 7;
    const int swc = (c7 * 8) ^ ((r0 & 7) << 3);

    f32x4 o[4] = {};
    float m2 = -INFINITY, l_run = 0.f;

    s16x8 sk0, sk1, sv0, sv1;

#define LOADG(t_) do {                                                       \
    const short* kt_ = kb + (size_t)(t_) * 64 * HH;                          \
    const short* vt_ = vb + (t_) * 64;                                       \
    sk0 = *reinterpret_cast<const s16x8*>(&kt_[r0 * HH + c7 * 8]);           \
    sk1 = *reinterpret_cast<const s16x8*>(&kt_[r1 * HH + c7 * 8]);           \
    sv0 = *reinterpret_cast<const s16x8*>(&vt_[(size_t)r0 * TT + c7 * 8]);   \
    sv1 = *reinterpret_cast<const s16x8*>(&vt_[(size_t)r1 * TT + c7 * 8]);   \
  } while (0)

#define WRITELDS(bf_) do {                                                   \
    *reinterpret_cast<s16x8*>(&kl[bf_][r0 * 64 + swc]) = sk0;                \
    *reinterpret_cast<s16x8*>(&kl[bf_][r1 * 64 + swc]) = sk1;                \
    *reinterpret_cast<s16x8*>(&vl[bf_][r0 * 64 + swc]) = sv0;                \
    *reinterpret_cast<s16x8*>(&vl[bf_][r1 * 64 + swc]) = sv1;                \
  } while (0)

    if (cnt > 0) {
        LOADG(s);
        WRITELDS(0);
        __syncthreads();

        for (int u = 0; u < cnt; ++u) {
            const int cur = u & 1;
            const int jt = s + 4 * u;
            if (u + 1 < cnt) LOADG(jt + 4);

            f32x4 sv[4] = {};
            __builtin_amdgcn_s_setprio(1);
#pragma unroll
            for (int k2 = 0; k2 < 2; ++k2)
#pragma unroll
                for (int n = 0; n < 4; ++n) {
                    const int row = n * 16 + lr;
                    const int sw = (row & 7) << 3;
                    s16x4 klo = *reinterpret_cast<const s16x4*>(&kl[cur][row * 64 + ((32 * k2 + 4 * lg) ^ sw)]);
                    s16x4 khi = *reinterpret_cast<const s16x4*>(&kl[cur][row * 64 + ((32 * k2 + 4 * lg + 16) ^ sw)]);
                    sv[n] = __builtin_amdgcn_mfma_f32_16x16x32_bf16(cat8(klo, khi), aQ[k2], sv[n], 0, 0, 0);
                }
            __builtin_amdgcn_s_setprio(0);

            if (jt == jq) { // diag tile
#pragma unroll
                for (int n = 0; n < 4; ++n)
#pragma unroll
                    for (int jj = 0; jj < 4; ++jj)
                        if (n * 16 + 4 * lg + jj > w * 16 + lr) sv[n][jj] = -3.0e38f;
            }

            float tm = fmaxf(fmaxf(fmaxf(sv[0][0], sv[0][1]), fmaxf(sv[0][2], sv[0][3])),
                             fmaxf(fmaxf(sv[1][0], sv[1][1]), fmaxf(sv[1][2], sv[1][3])));
            tm = fmaxf(tm, fmaxf(fmaxf(fmaxf(sv[2][0], sv[2][1]), fmaxf(sv[2][2], sv[2][3])),
                                 fmaxf(fmaxf(sv[3][0], sv[3][1]), fmaxf(sv[3][2], sv[3][3]))));
            tm = fmaxf(tm, __shfl_xor(tm, 16));
            tm = fmaxf(tm, __shfl_xor(tm, 32));

            if (!__all((tm * SC2 - m2) <= 8.f)) {   // T13 defer-max
                const float mnew = fmaxf(m2, tm * SC2);
                const float alpha = exp2f(m2 - mnew);
                m2 = mnew;
                l_run *= alpha;
                float alj[4];
#pragma unroll
                for (int jj = 0; jj < 4; ++jj) alj[jj] = __shfl(alpha, 4 * lg + jj);
#pragma unroll
                for (int n = 0; n < 4; ++n)
#pragma unroll
                    for (int jj = 0; jj < 4; ++jj)
                        o[n][jj] *= alj[jj];
            }

            float psum = 0.f;
#pragma unroll
            for (int n = 0; n < 4; ++n)
#pragma unroll
                for (int jj = 0; jj < 4; ++jj) {
                    float p = exp2f(fmaf(sv[n][jj], SC2, -m2));
                    sv[n][jj] = p;
                    psum += p;
                }
            psum += __shfl_xor(psum, 16);
            psum += __shfl_xor(psum, 32);
            l_run += psum;

            bf16x8 aP[2];
#pragma unroll
            for (int k2 = 0; k2 < 2; ++k2) {
                bf16x8 tt;
#pragma unroll
                for (int jj = 0; jj < 4; ++jj) {
                    tt[jj]     = f2bf(sv[2 * k2][jj]);
                    tt[4 + jj] = f2bf(sv[2 * k2 + 1][jj]);
                }
                aP[k2] = tt;
            }
            __builtin_amdgcn_s_setprio(1);
#pragma unroll
            for (int k2 = 0; k2 < 2; ++k2)
#pragma unroll
                for (int n = 0; n < 4; ++n) {
                    const int row = n * 16 + lr;
                    const int sw = (row & 7) << 3;
                    s16x4 vlo = *reinterpret_cast<const s16x4*>(&vl[cur][row * 64 + ((32 * k2 + 4 * lg) ^ sw)]);
                    s16x4 vhi = *reinterpret_cast<const s16x4*>(&vl[cur][row * 64 + ((32 * k2 + 4 * lg + 16) ^ sw)]);
                    o[n] = __builtin_amdgcn_mfma_f32_16x16x32_bf16(aP[k2], cat8(vlo, vhi), o[n], 0, 0, 0);
                }
            __builtin_amdgcn_s_setprio(0);

            if (u + 1 < cnt) WRITELDS(cur ^ 1);
            __syncthreads();
        }
    }
#undef LOADG
#undef WRITELDS

    short* opb = opb16 + (((size_t)s * BB + b) * TT + jq * 64 + w * 16) * HH;
#pragma unroll
    for (int n = 0; n < 4; ++n)
#pragma unroll
        for (int jj = 0; jj < 4; ++jj)
            opb[(size_t)(4 * lg + jj) * HH + n * 16 + lr] = f2bf(o[n][jj]);
    if (lg == 0) {
        const size_t mi = ((size_t)s * BB + b) * TT + jq * 64 + w * 16 + lr;
        mm[mi] = m2;
        ll[mi] = l_run;
    }
}

// ---------------- Kernel 3: merge the four kv-parity partials (bf16 in, fp32 out) ----------------
__global__ __launch_bounds__(256) void attn_merge4(
    const short* __restrict__ opb16, const float* __restrict__ mm,
    const float* __restrict__ ll, float* __restrict__ out)
{
    const int t = blockIdx.x * 256 + threadIdx.x; // 65536
    const int row = t >> 2;
    const int seg = (t & 3) * 16;
    const size_t BT = (size_t)BB * TT;

    float mw[4], lw[4];
#pragma unroll
    for (int w = 0; w < 4; ++w) { mw[w] = mm[w * BT + row]; lw[w] = ll[w * BT + row]; }
    const float M = fmaxf(fmaxf(mw[0], mw[1]), fmaxf(mw[2], mw[3]));
    float ew[4], L = 0.f;
#pragma unroll
    for (int w = 0; w < 4; ++w) { ew[w] = exp2f(mw[w] - M); L += ew[w] * lw[w]; }
    const float inv = 1.f / L;

    float accv[16];
#pragma unroll
    for (int u = 0; u < 16; ++u) accv[u] = 0.f;
#pragma unroll
    for (int w = 0; w < 4; ++w) {
        const short* pb = opb16 + ((w * BT + row) * HH + seg);
        s16x8 v0 = *reinterpret_cast<const s16x8*>(pb);
        s16x8 v1 = *reinterpret_cast<const s16x8*>(pb + 8);
#pragma unroll
        for (int u = 0; u < 8; ++u) {
            accv[u]     += ew[w] * bf2f(v0[u]);
            accv[8 + u] += ew[w] * bf2f(v1[u]);
        }
    }
    float* po = out + (size_t)row * HH + seg;
#pragma unroll
    for (int u = 0; u < 4; ++u) {
        float4 rr = { accv[4 * u] * inv, accv[4 * u + 1] * inv,
                      accv[4 * u + 2] * inv, accv[4 * u + 3] * inv };
        *reinterpret_cast<float4*>(po + 4 * u) = rr;
    }
}

extern "C" void kernel_launch(void* const* d_in, const int* in_sizes, int n_in,
                              void* d_out, int out_size, void* d_ws, size_t ws_size,
                              hipStream_t stream) {
    const float* x  = (const float*)d_in[0];
    const float* Wk = (const float*)d_in[1];
    const float* Wq = (const float*)d_in[2];
    const float* Wv = (const float*)d_in[3];
    float* outp = (float*)d_out;

    const size_t n = (size_t)BB * TT * HH; // 1,048,576
    short* kbuf  = (short*)d_ws;
    short* qbuf  = kbuf + n;
    short* vbuf  = qbuf + n;                // vT layout [B][H][T]
    short* wbf   = vbuf + n;                // 196,608 bf16 weights
    short* opb16 = wbf + 196608;            // [4][B][T][H] bf16 partials (8 MB)
    float* mm    = (float*)(opb16 + 4 * n); // [4][B][T]
    float* ll    = mm + 4 * BB * TT;

    wconv<<<192, 256, 0, stream>>>(Wk, Wq, Wv, wbf);
    proj_fused<<<512, 256, 0, stream>>>(x, wbf, kbuf, qbuf, vbuf);
    attn_split<<<1024, 256, 0, stream>>>(qbuf, kbuf, vbuf, opb16, mm, ll);
    attn_merge4<<<256, 256, 0, stream>>>(opb16, mm, ll, outp);
}

// Round 27
// 54.045 us; speedup vs baseline: 1.0196x; 1.0152x over previous
//
#include <hip/hip_runtime.h>
#include <math.h>

#define BB 8
#define TT 2048
#define CC 1024
#define HH 64
constexpr float SC2 = 0.03125f * 1.4426950408889634f; // (1/sqrt(1024)) * log2(e)

typedef __attribute__((ext_vector_type(8))) short bf16x8;
typedef __attribute__((ext_vector_type(8))) short s16x8;
typedef __attribute__((ext_vector_type(4))) short s16x4;
typedef __attribute__((ext_vector_type(4))) float f32x4;

static __device__ __forceinline__ short f2bf(float f) {
    union { float f; unsigned u; } un; un.f = f;
    unsigned r = un.u + 0x7FFFu + ((un.u >> 16) & 1u); // RNE
    return (short)(r >> 16);
}
static __device__ __forceinline__ float bf2f(short h) {
    union { unsigned u; float f; } un; un.u = ((unsigned)(unsigned short)h) << 16;
    return un.f;
}
static __device__ __forceinline__ bf16x8 cat8(s16x4 lo, s16x4 hi) {
    return __builtin_shufflevector(lo, hi, 0, 1, 2, 3, 4, 5, 6, 7);
}

// ---------------- Kernel 0: W fp32 -> bf16 (concatenated [192][1024]) ----------------
__global__ __launch_bounds__(256) void wconv(
    const float* __restrict__ Wk, const float* __restrict__ Wq, const float* __restrict__ Wv,
    short* __restrict__ wbf)
{
    const int i = blockIdx.x * 256 + threadIdx.x;
    const int elem = i * 4;
    const int mat = elem >> 16;
    const int off = elem & 65535;
    const float* W = (mat == 0) ? Wk : (mat == 1) ? Wq : Wv;
    float4 w4 = *reinterpret_cast<const float4*>(&W[off]);
    s16x4 h = { f2bf(w4.x), f2bf(w4.y), f2bf(w4.z), f2bf(w4.w) };
    *reinterpret_cast<s16x4*>(&wbf[elem]) = h;
}

// ---------------- Kernel 1: qkv projection, BM=64 x BN=96, 3 blocks/CU ----------------
__global__ __launch_bounds__(256) void proj_fused(
    const float* __restrict__ x, const short* __restrict__ wbf,
    short* __restrict__ ko, short* __restrict__ qo, short* __restrict__ vT)
{
    __shared__ short At[2][64][72];   // 18KB
    __shared__ short Bt[2][96][72];   // 27KB

    const int tid  = threadIdx.x;
    const int rb   = blockIdx.x >> 1;
    const int nh   = blockIdx.x & 1;      // n-half: cols [96*nh, 96*nh+96)
    const int row0 = rb * 64;
    const int wv = tid >> 6, lane = tid & 63;
    const int wm = wv >> 1, wn = wv & 1;  // 32-row half x 48-col half
    const int lr = lane & 15, lg = lane >> 4;

    const int br_ = tid >> 3;             // B staging: rows br_+32*it, 3 iters
    const int bc8 = (tid & 7) * 8;
    const short* wb = wbf + (size_t)nh * 96 * CC;

    f32x4 acc[2][3] = {};
    float4 axA[4], axB[4];
    s16x8 bwA[3], bwB[3];

#define PL(AX, BW, k0_) do {                                                           \
    _Pragma("unroll")                                                                  \
    for (int it = 0; it < 4; ++it) {                                                   \
        int idx_ = tid + 256 * it;                                                     \
        AX[it] = *reinterpret_cast<const float4*>(                                     \
            &x[(size_t)(row0 + (idx_ >> 4)) * CC + (k0_) + (idx_ & 15) * 4]);          \
    }                                                                                  \
    _Pragma("unroll")                                                                  \
    for (int it = 0; it < 3; ++it)                                                     \
        BW[it] = *reinterpret_cast<const s16x8*>(&wb[(size_t)(br_ + 32 * it) * CC + (k0_) + bc8]); \
  } while (0)

#define PW(bf_, AX, BW) do {                                                           \
    _Pragma("unroll")                                                                  \
    for (int it = 0; it < 4; ++it) {                                                   \
        int idx_ = tid + 256 * it;                                                     \
        s16x4 h_ = { f2bf(AX[it].x), f2bf(AX[it].y), f2bf(AX[it].z), f2bf(AX[it].w) }; \
        *reinterpret_cast<s16x4*>(&At[bf_][idx_ >> 4][(idx_ & 15) * 4]) = h_;          \
    }                                                                                  \
    _Pragma("unroll")                                                                  \
    for (int it = 0; it < 3; ++it)                                                     \
        *reinterpret_cast<s16x8*>(&Bt[bf_][br_ + 32 * it][bc8]) = BW[it];              \
  } while (0)

#define PCOMP(bf_) do {                                                                \
    _Pragma("unroll")                                                                  \
    for (int kk = 0; kk < 64; kk += 32) {                                              \
        bf16x8 aF[2], bF[3];                                                           \
        _Pragma("unroll")                                                              \
        for (int m = 0; m < 2; ++m) {                                                  \
            const int row_ = wm * 32 + m * 16 + lr;                                    \
            aF[m] = cat8(*reinterpret_cast<const s16x4*>(&At[bf_][row_][kk + 4 * lg]), \
                         *reinterpret_cast<const s16x4*>(&At[bf_][row_][kk + 16 + 4 * lg])); \
        }                                                                              \
        _Pragma("unroll")                                                              \
        for (int n = 0; n < 3; ++n) {                                                  \
            const int brow_ = wn * 48 + n * 16 + lr;                                   \
            bF[n] = cat8(*reinterpret_cast<const s16x4*>(&Bt[bf_][brow_][kk + 4 * lg]),\
                         *reinterpret_cast<const s16x4*>(&Bt[bf_][brow_][kk + 16 + 4 * lg])); \
        }                                                                              \
        _Pragma("unroll")                                                              \
        for (int m = 0; m < 2; ++m)                                                    \
            _Pragma("unroll")                                                          \
            for (int n = 0; n < 3; ++n)                                                \
                acc[m][n] = __builtin_amdgcn_mfma_f32_16x16x32_bf16(aF[m], bF[n], acc[m][n], 0, 0, 0); \
    }                                                                                  \
  } while (0)

    PL(axA, bwA, 0);
    PL(axB, bwB, 64);
    PW(0, axA, bwA);
    __syncthreads();

#pragma unroll
    for (int ks = 0; ks < 16; ks += 2) {
        if (ks + 2 < 16) PL(axA, bwA, (ks + 2) * 64);
        PCOMP(0);
        PW(1, axB, bwB);
        __syncthreads();
        if (ks + 3 < 16) PL(axB, bwB, (ks + 3) * 64);
        PCOMP(1);
        if (ks + 2 < 16) PW(0, axA, bwA);
        __syncthreads();
    }
#undef PL
#undef PW
#undef PCOMP

    const int bb = row0 >> 11;
    const int t0 = row0 & 2047;
#pragma unroll
    for (int m = 0; m < 2; ++m)
#pragma unroll
        for (int n = 0; n < 3; ++n) {
            const int col0 = nh * 96 + wn * 48 + n * 16;  // 16-aligned, single matrix
            const int mat  = col0 >> 6;
            const int hcol = (col0 & 63) + lr;
            const int trow = wm * 32 + m * 16 + 4 * lg;
            if (mat == 2) {
                s16x4 pk = { f2bf(acc[m][n][0]), f2bf(acc[m][n][1]),
                             f2bf(acc[m][n][2]), f2bf(acc[m][n][3]) };
                *reinterpret_cast<s16x4*>(&vT[((size_t)bb * HH + hcol) * TT + t0 + trow]) = pk;
            } else {
                short* o = (mat == 0) ? ko : qo;
#pragma unroll
                for (int j = 0; j < 4; ++j)
                    o[(size_t)(row0 + trow + j) * HH + hcol] = f2bf(acc[m][n][j]);
            }
        }
}

// ---------------- Kernel 2: causal flash attention, parity-4 + XCD b-locality + defer-max ----------------
// (setprio REMOVED: m190 regime — 4-wave barrier-synced blocks are lockstep, setprio hurts)
__global__ __launch_bounds__(256) void attn_split(
    const short* __restrict__ q, const short* __restrict__ k,
    const short* __restrict__ vT, short* __restrict__ opb16,
    float* __restrict__ mm, float* __restrict__ ll)
{
    __shared__ short kl[2][4096];  // [kv][h] swizzled
    __shared__ short vl[2][4096];  // [h][t]  swizzled

    const int tid = threadIdx.x;
    const int w = tid >> 6, lane = tid & 63;
    const int lr = lane & 15, lg = lane >> 4;

    const int idx = blockIdx.x;
    const int b = idx & 7;          // XCD-locality: one batch per XCD
    const int j = idx >> 3;
    int jq, s;
    if (j < 64) { jq = j >> 2;              s = j & 3; }
    else        { jq = 31 - ((j - 64) >> 2); s = j & 3; }
    const int cnt = (jq >= s) ? ((jq - s) >> 2) + 1 : 0;

    const short* qb = q  + ((size_t)b * TT + jq * 64 + w * 16) * HH;
    const short* kb = k  + (size_t)b * TT * HH;   // [t][h]
    const short* vb = vT + (size_t)b * HH * TT;   // [h][t]

    bf16x8 aQ[2];
#pragma unroll
    for (int k2 = 0; k2 < 2; ++k2)
        aQ[k2] = cat8(*reinterpret_cast<const s16x4*>(&qb[lr * HH + k2 * 32 + 4 * lg]),
                      *reinterpret_cast<const s16x4*>(&qb[lr * HH + k2 * 32 + 16 + 4 * lg]));

    const int r0 = w * 16 + (lane >> 3);
    const int r1 = r0 + 8;
    const int c7 = lane & 7;
    const int swc = (c7 * 8) ^ ((r0 & 7) << 3);

    f32x4 o[4] = {};
    float m2 = -INFINITY, l_run = 0.f;

    s16x8 sk0, sk1, sv0, sv1;

#define LOADG(t_) do {                                                       \
    const short* kt_ = kb + (size_t)(t_) * 64 * HH;                          \
    const short* vt_ = vb + (t_) * 64;                                       \
    sk0 = *reinterpret_cast<const s16x8*>(&kt_[r0 * HH + c7 * 8]);           \
    sk1 = *reinterpret_cast<const s16x8*>(&kt_[r1 * HH + c7 * 8]);           \
    sv0 = *reinterpret_cast<const s16x8*>(&vt_[(size_t)r0 * TT + c7 * 8]);   \
    sv1 = *reinterpret_cast<const s16x8*>(&vt_[(size_t)r1 * TT + c7 * 8]);   \
  } while (0)

#define WRITELDS(bf_) do {                                                   \
    *reinterpret_cast<s16x8*>(&kl[bf_][r0 * 64 + swc]) = sk0;                \
    *reinterpret_cast<s16x8*>(&kl[bf_][r1 * 64 + swc]) = sk1;                \
    *reinterpret_cast<s16x8*>(&vl[bf_][r0 * 64 + swc]) = sv0;                \
    *reinterpret_cast<s16x8*>(&vl[bf_][r1 * 64 + swc]) = sv1;                \
  } while (0)

    if (cnt > 0) {
        LOADG(s);
        WRITELDS(0);
        __syncthreads();

        for (int u = 0; u < cnt; ++u) {
            const int cur = u & 1;
            const int jt = s + 4 * u;
            if (u + 1 < cnt) LOADG(jt + 4);

            f32x4 sv[4] = {};
#pragma unroll
            for (int k2 = 0; k2 < 2; ++k2)
#pragma unroll
                for (int n = 0; n < 4; ++n) {
                    const int row = n * 16 + lr;
                    const int sw = (row & 7) << 3;
                    s16x4 klo = *reinterpret_cast<const s16x4*>(&kl[cur][row * 64 + ((32 * k2 + 4 * lg) ^ sw)]);
                    s16x4 khi = *reinterpret_cast<const s16x4*>(&kl[cur][row * 64 + ((32 * k2 + 4 * lg + 16) ^ sw)]);
                    sv[n] = __builtin_amdgcn_mfma_f32_16x16x32_bf16(cat8(klo, khi), aQ[k2], sv[n], 0, 0, 0);
                }

            if (jt == jq) { // diag tile
#pragma unroll
                for (int n = 0; n < 4; ++n)
#pragma unroll
                    for (int jj = 0; jj < 4; ++jj)
                        if (n * 16 + 4 * lg + jj > w * 16 + lr) sv[n][jj] = -3.0e38f;
            }

            float tm = fmaxf(fmaxf(fmaxf(sv[0][0], sv[0][1]), fmaxf(sv[0][2], sv[0][3])),
                             fmaxf(fmaxf(sv[1][0], sv[1][1]), fmaxf(sv[1][2], sv[1][3])));
            tm = fmaxf(tm, fmaxf(fmaxf(fmaxf(sv[2][0], sv[2][1]), fmaxf(sv[2][2], sv[2][3])),
                                 fmaxf(fmaxf(sv[3][0], sv[3][1]), fmaxf(sv[3][2], sv[3][3]))));
            tm = fmaxf(tm, __shfl_xor(tm, 16));
            tm = fmaxf(tm, __shfl_xor(tm, 32));

            if (!__all((tm * SC2 - m2) <= 8.f)) {   // T13 defer-max
                const float mnew = fmaxf(m2, tm * SC2);
                const float alpha = exp2f(m2 - mnew);
                m2 = mnew;
                l_run *= alpha;
                float alj[4];
#pragma unroll
                for (int jj = 0; jj < 4; ++jj) alj[jj] = __shfl(alpha, 4 * lg + jj);
#pragma unroll
                for (int n = 0; n < 4; ++n)
#pragma unroll
                    for (int jj = 0; jj < 4; ++jj)
                        o[n][jj] *= alj[jj];
            }

            float psum = 0.f;
#pragma unroll
            for (int n = 0; n < 4; ++n)
#pragma unroll
                for (int jj = 0; jj < 4; ++jj) {
                    float p = exp2f(fmaf(sv[n][jj], SC2, -m2));
                    sv[n][jj] = p;
                    psum += p;
                }
            psum += __shfl_xor(psum, 16);
            psum += __shfl_xor(psum, 32);
            l_run += psum;

            bf16x8 aP[2];
#pragma unroll
            for (int k2 = 0; k2 < 2; ++k2) {
                bf16x8 tt;
#pragma unroll
                for (int jj = 0; jj < 4; ++jj) {
                    tt[jj]     = f2bf(sv[2 * k2][jj]);
                    tt[4 + jj] = f2bf(sv[2 * k2 + 1][jj]);
                }
                aP[k2] = tt;
            }
#pragma unroll
            for (int k2 = 0; k2 < 2; ++k2)
#pragma unroll
                for (int n = 0; n < 4; ++n) {
                    const int row = n * 16 + lr;
                    const int sw = (row & 7) << 3;
                    s16x4 vlo = *reinterpret_cast<const s16x4*>(&vl[cur][row * 64 + ((32 * k2 + 4 * lg) ^ sw)]);
                    s16x4 vhi = *reinterpret_cast<const s16x4*>(&vl[cur][row * 64 + ((32 * k2 + 4 * lg + 16) ^ sw)]);
                    o[n] = __builtin_amdgcn_mfma_f32_16x16x32_bf16(aP[k2], cat8(vlo, vhi), o[n], 0, 0, 0);
                }

            if (u + 1 < cnt) WRITELDS(cur ^ 1);
            __syncthreads();
        }
    }
#undef LOADG
#undef WRITELDS

    short* opb = opb16 + (((size_t)s * BB + b) * TT + jq * 64 + w * 16) * HH;
#pragma unroll
    for (int n = 0; n < 4; ++n)
#pragma unroll
        for (int jj = 0; jj < 4; ++jj)
            opb[(size_t)(4 * lg + jj) * HH + n * 16 + lr] = f2bf(o[n][jj]);
    if (lg == 0) {
        const size_t mi = ((size_t)s * BB + b) * TT + jq * 64 + w * 16 + lr;
        mm[mi] = m2;
        ll[mi] = l_run;
    }
}

// ---------------- Kernel 3: merge the four kv-parity partials (bf16 in, fp32 out) ----------------
__global__ __launch_bounds__(256) void attn_merge4(
    const short* __restrict__ opb16, const float* __restrict__ mm,
    const float* __restrict__ ll, float* __restrict__ out)
{
    const int t = blockIdx.x * 256 + threadIdx.x; // 65536
    const int row = t >> 2;
    const int seg = (t & 3) * 16;
    const size_t BT = (size_t)BB * TT;

    float mw[4], lw[4];
#pragma unroll
    for (int w = 0; w < 4; ++w) { mw[w] = mm[w * BT + row]; lw[w] = ll[w * BT + row]; }
    const float M = fmaxf(fmaxf(mw[0], mw[1]), fmaxf(mw[2], mw[3]));
    float ew[4], L = 0.f;
#pragma unroll
    for (int w = 0; w < 4; ++w) { ew[w] = exp2f(mw[w] - M); L += ew[w] * lw[w]; }
    const float inv = 1.f / L;

    float accv[16];
#pragma unroll
    for (int u = 0; u < 16; ++u) accv[u] = 0.f;
#pragma unroll
    for (int w = 0; w < 4; ++w) {
        const short* pb = opb16 + ((w * BT + row) * HH + seg);
        s16x8 v0 = *reinterpret_cast<const s16x8*>(pb);
        s16x8 v1 = *reinterpret_cast<const s16x8*>(pb + 8);
#pragma unroll
        for (int u = 0; u < 8; ++u) {
            accv[u]     += ew[w] * bf2f(v0[u]);
            accv[8 + u] += ew[w] * bf2f(v1[u]);
        }
    }
    float* po = out + (size_t)row * HH + seg;
#pragma unroll
    for (int u = 0; u < 4; ++u) {
        float4 rr = { accv[4 * u] * inv, accv[4 * u + 1] * inv,
                      accv[4 * u + 2] * inv, accv[4 * u + 3] * inv };
        *reinterpret_cast<float4*>(po + 4 * u) = rr;
    }
}

extern "C" void kernel_launch(void* const* d_in, const int* in_sizes, int n_in,
                              void* d_out, int out_size, void* d_ws, size_t ws_size,
                              hipStream_t stream) {
    const float* x  = (const float*)d_in[0];
    const float* Wk = (const float*)d_in[1];
    const float* Wq = (const float*)d_in[2];
    const float* Wv = (const float*)d_in[3];
    float* outp = (float*)d_out;

    const size_t n = (size_t)BB * TT * HH; // 1,048,576
    short* kbuf  = (short*)d_ws;
    short* qbuf  = kbuf + n;
    short* vbuf  = qbuf + n;                // vT layout [B][H][T]
    short* wbf   = vbuf + n;                // 196,608 bf16 weights
    short* opb16 = wbf + 196608;            // [4][B][T][H] bf16 partials (8 MB)
    float* mm    = (float*)(opb16 + 4 * n); // [4][B][T]
    float* ll    = mm + 4 * BB * TT;

    wconv<<<192, 256, 0, stream>>>(Wk, Wq, Wv, wbf);
    proj_fused<<<512, 256, 0, stream>>>(x, wbf, kbuf, qbuf, vbuf);
    attn_split<<<1024, 256, 0, stream>>>(qbuf, kbuf, vbuf, opb16, mm, ll);
    attn_merge4<<<256, 256, 0, stream>>>(opb16, mm, ll, outp);
}

// Round 28
// 51.478 us; speedup vs baseline: 1.0704x; 1.0499x over previous
//
#include <hip/hip_runtime.h>
#include <math.h>

#define BB 8
#define TT 2048
#define CC 1024
#define HH 64
constexpr float SC2 = 0.03125f * 1.4426950408889634f; // (1/sqrt(1024)) * log2(e)

typedef __attribute__((ext_vector_type(8))) short bf16x8;
typedef __attribute__((ext_vector_type(8))) short s16x8;
typedef __attribute__((ext_vector_type(4))) short s16x4;
typedef __attribute__((ext_vector_type(4))) float f32x4;

static __device__ __forceinline__ short f2bf(float f) {
    union { float f; unsigned u; } un; un.f = f;
    unsigned r = un.u + 0x7FFFu + ((un.u >> 16) & 1u); // RNE
    return (short)(r >> 16);
}
static __device__ __forceinline__ float bf2f(short h) {
    union { unsigned u; float f; } un; un.u = ((unsigned)(unsigned short)h) << 16;
    return un.f;
}
static __device__ __forceinline__ bf16x8 cat8(s16x4 lo, s16x4 hi) {
    return __builtin_shufflevector(lo, hi, 0, 1, 2, 3, 4, 5, 6, 7);
}

// Soft barrier: LDS-drain + raw s_barrier. Unlike __syncthreads (which emits
// s_waitcnt vmcnt(0) lgkmcnt(0)), this leaves global prefetch loads IN FLIGHT
// across the barrier (T4 counted-vmcnt principle). Safe here: the only cross-wave
// hazard is LDS write->read (drained by lgkmcnt(0)); in-flight global loads are
// read-only x/W/k/v and their register use is compiler-waited with counted vmcnt.
#define SOFTSYNC() do {                                         \
    asm volatile("s_waitcnt lgkmcnt(0)" ::: "memory");          \
    __builtin_amdgcn_s_barrier();                               \
    __builtin_amdgcn_sched_barrier(0);                          \
  } while (0)

// ---------------- Kernel 0: W fp32 -> bf16 (concatenated [192][1024]) ----------------
__global__ __launch_bounds__(256) void wconv(
    const float* __restrict__ Wk, const float* __restrict__ Wq, const float* __restrict__ Wv,
    short* __restrict__ wbf)
{
    const int i = blockIdx.x * 256 + threadIdx.x;
    const int elem = i * 4;
    const int mat = elem >> 16;
    const int off = elem & 65535;
    const float* W = (mat == 0) ? Wk : (mat == 1) ? Wq : Wv;
    float4 w4 = *reinterpret_cast<const float4*>(&W[off]);
    s16x4 h = { f2bf(w4.x), f2bf(w4.y), f2bf(w4.z), f2bf(w4.w) };
    *reinterpret_cast<s16x4*>(&wbf[elem]) = h;
}

// ---------------- Kernel 1: qkv projection, BM=32 (r22 layout) + soft barriers ----------------
// 512 blocks x 32 rows, 2 blocks/CU, 2-deep prefetch, dbuf LDS.
__global__ __launch_bounds__(256) void proj_fused(
    const float* __restrict__ x, const short* __restrict__ wbf,
    short* __restrict__ ko, short* __restrict__ qo, short* __restrict__ vT)
{
    __shared__ short At[2][32][72];
    __shared__ short Bt[2][192][72];

    const int tid  = threadIdx.x;
    const int row0 = blockIdx.x * 32;
    const int wv = tid >> 6, lane = tid & 63;
    const int lr = lane & 15, lg = lane >> 4;

    const int ar  = tid >> 4;            // A rows: ar, ar+16
    const int ac4 = (tid & 15) * 4;
    const int br_ = tid >> 3;            // B rows: br_+32*it
    const int bc8 = (tid & 7) * 8;

    f32x4 acc[2][3] = {};
    float4 axA0, axA1, axB0, axB1;
    s16x8 bwA[6], bwB[6];

#define PL(AX0, AX1, BW, k0_) do {                                                     \
    AX0 = *reinterpret_cast<const float4*>(&x[(size_t)(row0 + ar) * CC + (k0_) + ac4]);       \
    AX1 = *reinterpret_cast<const float4*>(&x[(size_t)(row0 + ar + 16) * CC + (k0_) + ac4]);  \
    _Pragma("unroll")                                                                  \
    for (int it = 0; it < 6; ++it)                                                     \
        BW[it] = *reinterpret_cast<const s16x8*>(&wbf[(size_t)(br_ + 32 * it) * CC + (k0_) + bc8]); \
  } while (0)

#define PW(bf_, AX0, AX1, BW) do {                                                     \
    s16x4 h0 = { f2bf(AX0.x), f2bf(AX0.y), f2bf(AX0.z), f2bf(AX0.w) };                 \
    s16x4 h1 = { f2bf(AX1.x), f2bf(AX1.y), f2bf(AX1.z), f2bf(AX1.w) };                 \
    *reinterpret_cast<s16x4*>(&At[bf_][ar][ac4]) = h0;                                 \
    *reinterpret_cast<s16x4*>(&At[bf_][ar + 16][ac4]) = h1;                            \
    _Pragma("unroll")                                                                  \
    for (int it = 0; it < 6; ++it)                                                     \
        *reinterpret_cast<s16x8*>(&Bt[bf_][br_ + 32 * it][bc8]) = BW[it];              \
  } while (0)

#define PCOMP(bf_) do {                                                                \
    _Pragma("unroll")                                                                  \
    for (int kk = 0; kk < 64; kk += 32) {                                              \
        bf16x8 aF[2], bF[3];                                                           \
        _Pragma("unroll")                                                              \
        for (int m = 0; m < 2; ++m) {                                                  \
            const int row_ = m * 16 + lr;                                              \
            aF[m] = cat8(*reinterpret_cast<const s16x4*>(&At[bf_][row_][kk + 4 * lg]), \
                         *reinterpret_cast<const s16x4*>(&At[bf_][row_][kk + 16 + 4 * lg])); \
        }                                                                              \
        _Pragma("unroll")                                                              \
        for (int n = 0; n < 3; ++n) {                                                  \
            const int brow_ = wv * 48 + n * 16 + lr;                                   \
            bF[n] = cat8(*reinterpret_cast<const s16x4*>(&Bt[bf_][brow_][kk + 4 * lg]),\
                         *reinterpret_cast<const s16x4*>(&Bt[bf_][brow_][kk + 16 + 4 * lg])); \
        }                                                                              \
        _Pragma("unroll")                                                              \
        for (int m = 0; m < 2; ++m)                                                    \
            _Pragma("unroll")                                                          \
            for (int n = 0; n < 3; ++n)                                                \
                acc[m][n] = __builtin_amdgcn_mfma_f32_16x16x32_bf16(aF[m], bF[n], acc[m][n], 0, 0, 0); \
    }                                                                                  \
  } while (0)

    PL(axA0, axA1, bwA, 0);      // tile 0
    PL(axB0, axB1, bwB, 64);     // tile 1
    PW(0, axA0, axA1, bwA);      // LDS buf0 <- tile 0
    SOFTSYNC();

#pragma unroll
    for (int ks = 0; ks < 16; ks += 2) {
        if (ks + 2 < 16) PL(axA0, axA1, bwA, (ks + 2) * 64);
        PCOMP(0);
        PW(1, axB0, axB1, bwB);
        SOFTSYNC();
        if (ks + 3 < 16) PL(axB0, axB1, bwB, (ks + 3) * 64);
        PCOMP(1);
        if (ks + 2 < 16) PW(0, axA0, axA1, bwA);
        SOFTSYNC();
    }
#undef PL
#undef PW
#undef PCOMP

    const int bb = row0 >> 11;
    const int t0 = row0 & 2047;
#pragma unroll
    for (int m = 0; m < 2; ++m)
#pragma unroll
        for (int n = 0; n < 3; ++n) {
            const int col0 = wv * 48 + n * 16;
            const int mat  = col0 >> 6;
            const int hcol = (col0 & 63) + lr;
            const int trow = m * 16 + 4 * lg;
            if (mat == 2) {
                s16x4 pk = { f2bf(acc[m][n][0]), f2bf(acc[m][n][1]),
                             f2bf(acc[m][n][2]), f2bf(acc[m][n][3]) };
                *reinterpret_cast<s16x4*>(&vT[((size_t)bb * HH + hcol) * TT + t0 + trow]) = pk;
            } else {
                short* o = (mat == 0) ? ko : qo;
#pragma unroll
                for (int j = 0; j < 4; ++j)
                    o[(size_t)(row0 + trow + j) * HH + hcol] = f2bf(acc[m][n][j]);
            }
        }
}

// ---------------- Kernel 2: causal flash attention, parity-4 + XCD b-locality + defer-max ----------------
// soft barriers (lgkmcnt-only) keep K/V prefetch loads in flight across the per-tile sync.
__global__ __launch_bounds__(256) void attn_split(
    const short* __restrict__ q, const short* __restrict__ k,
    const short* __restrict__ vT, short* __restrict__ opb16,
    float* __restrict__ mm, float* __restrict__ ll)
{
    __shared__ short kl[2][4096];  // [kv][h] swizzled
    __shared__ short vl[2][4096];  // [h][t]  swizzled

    const int tid = threadIdx.x;
    const int w = tid >> 6, lane = tid & 63;
    const int lr = lane & 15, lg = lane >> 4;

    const int idx = blockIdx.x;
    const int b = idx & 7;          // XCD-locality: one batch per XCD
    const int j = idx >> 3;
    int jq, s;
    if (j < 64) { jq = j >> 2;              s = j & 3; }
    else        { jq = 31 - ((j - 64) >> 2); s = j & 3; }
    const int cnt = (jq >= s) ? ((jq - s) >> 2) + 1 : 0;

    const short* qb = q  + ((size_t)b * TT + jq * 64 + w * 16) * HH;
    const short* kb = k  + (size_t)b * TT * HH;   // [t][h]
    const short* vb = vT + (size_t)b * HH * TT;   // [h][t]

    bf16x8 aQ[2];
#pragma unroll
    for (int k2 = 0; k2 < 2; ++k2)
        aQ[k2] = cat8(*reinterpret_cast<const s16x4*>(&qb[lr * HH + k2 * 32 + 4 * lg]),
                      *reinterpret_cast<const s16x4*>(&qb[lr * HH + k2 * 32 + 16 + 4 * lg]));

    const int r0 = w * 16 + (lane >> 3);
    const int r1 = r0 + 8;
    const int c7 = lane & 7;
    const int swc = (c7 * 8) ^ ((r0 & 7) << 3);

    f32x4 o[4] = {};
    float m2 = -INFINITY, l_run = 0.f;

    s16x8 sk0, sk1, sv0, sv1;

#define LOADG(t_) do {                                                       \
    const short* kt_ = kb + (size_t)(t_) * 64 * HH;                          \
    const short* vt_ = vb + (t_) * 64;                                       \
    sk0 = *reinterpret_cast<const s16x8*>(&kt_[r0 * HH + c7 * 8]);           \
    sk1 = *reinterpret_cast<const s16x8*>(&kt_[r1 * HH + c7 * 8]);           \
    sv0 = *reinterpret_cast<const s16x8*>(&vt_[(size_t)r0 * TT + c7 * 8]);   \
    sv1 = *reinterpret_cast<const s16x8*>(&vt_[(size_t)r1 * TT + c7 * 8]);   \
  } while (0)

#define WRITELDS(bf_) do {                                                   \
    *reinterpret_cast<s16x8*>(&kl[bf_][r0 * 64 + swc]) = sk0;                \
    *reinterpret_cast<s16x8*>(&kl[bf_][r1 * 64 + swc]) = sk1;                \
    *reinterpret_cast<s16x8*>(&vl[bf_][r0 * 64 + swc]) = sv0;                \
    *reinterpret_cast<s16x8*>(&vl[bf_][r1 * 64 + swc]) = sv1;                \
  } while (0)

    if (cnt > 0) {
        LOADG(s);
        WRITELDS(0);
        SOFTSYNC();

        for (int u = 0; u < cnt; ++u) {
            const int cur = u & 1;
            const int jt = s + 4 * u;
            if (u + 1 < cnt) LOADG(jt + 4);

            f32x4 sv[4] = {};
#pragma unroll
            for (int k2 = 0; k2 < 2; ++k2)
#pragma unroll
                for (int n = 0; n < 4; ++n) {
                    const int row = n * 16 + lr;
                    const int sw = (row & 7) << 3;
                    s16x4 klo = *reinterpret_cast<const s16x4*>(&kl[cur][row * 64 + ((32 * k2 + 4 * lg) ^ sw)]);
                    s16x4 khi = *reinterpret_cast<const s16x4*>(&kl[cur][row * 64 + ((32 * k2 + 4 * lg + 16) ^ sw)]);
                    sv[n] = __builtin_amdgcn_mfma_f32_16x16x32_bf16(cat8(klo, khi), aQ[k2], sv[n], 0, 0, 0);
                }

            if (jt == jq) { // diag tile
#pragma unroll
                for (int n = 0; n < 4; ++n)
#pragma unroll
                    for (int jj = 0; jj < 4; ++jj)
                        if (n * 16 + 4 * lg + jj > w * 16 + lr) sv[n][jj] = -3.0e38f;
            }

            float tm = fmaxf(fmaxf(fmaxf(sv[0][0], sv[0][1]), fmaxf(sv[0][2], sv[0][3])),
                             fmaxf(fmaxf(sv[1][0], sv[1][1]), fmaxf(sv[1][2], sv[1][3])));
            tm = fmaxf(tm, fmaxf(fmaxf(fmaxf(sv[2][0], sv[2][1]), fmaxf(sv[2][2], sv[2][3])),
                                 fmaxf(fmaxf(sv[3][0], sv[3][1]), fmaxf(sv[3][2], sv[3][3]))));
            tm = fmaxf(tm, __shfl_xor(tm, 16));
            tm = fmaxf(tm, __shfl_xor(tm, 32));

            if (!__all((tm * SC2 - m2) <= 8.f)) {   // T13 defer-max
                const float mnew = fmaxf(m2, tm * SC2);
                const float alpha = exp2f(m2 - mnew);
                m2 = mnew;
                l_run *= alpha;
                float alj[4];
#pragma unroll
                for (int jj = 0; jj < 4; ++jj) alj[jj] = __shfl(alpha, 4 * lg + jj);
#pragma unroll
                for (int n = 0; n < 4; ++n)
#pragma unroll
                    for (int jj = 0; jj < 4; ++jj)
                        o[n][jj] *= alj[jj];
            }

            float psum = 0.f;
#pragma unroll
            for (int n = 0; n < 4; ++n)
#pragma unroll
                for (int jj = 0; jj < 4; ++jj) {
                    float p = exp2f(fmaf(sv[n][jj], SC2, -m2));
                    sv[n][jj] = p;
                    psum += p;
                }
            psum += __shfl_xor(psum, 16);
            psum += __shfl_xor(psum, 32);
            l_run += psum;

            bf16x8 aP[2];
#pragma unroll
            for (int k2 = 0; k2 < 2; ++k2) {
                bf16x8 tt;
#pragma unroll
                for (int jj = 0; jj < 4; ++jj) {
                    tt[jj]     = f2bf(sv[2 * k2][jj]);
                    tt[4 + jj] = f2bf(sv[2 * k2 + 1][jj]);
                }
                aP[k2] = tt;
            }
#pragma unroll
            for (int k2 = 0; k2 < 2; ++k2)
#pragma unroll
                for (int n = 0; n < 4; ++n) {
                    const int row = n * 16 + lr;
                    const int sw = (row & 7) << 3;
                    s16x4 vlo = *reinterpret_cast<const s16x4*>(&vl[cur][row * 64 + ((32 * k2 + 4 * lg) ^ sw)]);
                    s16x4 vhi = *reinterpret_cast<const s16x4*>(&vl[cur][row * 64 + ((32 * k2 + 4 * lg + 16) ^ sw)]);
                    o[n] = __builtin_amdgcn_mfma_f32_16x16x32_bf16(aP[k2], cat8(vlo, vhi), o[n], 0, 0, 0);
                }

            if (u + 1 < cnt) WRITELDS(cur ^ 1);
            SOFTSYNC();
        }
    }
#undef LOADG
#undef WRITELDS

    short* opb = opb16 + (((size_t)s * BB + b) * TT + jq * 64 + w * 16) * HH;
#pragma unroll
    for (int n = 0; n < 4; ++n)
#pragma unroll
        for (int jj = 0; jj < 4; ++jj)
            opb[(size_t)(4 * lg + jj) * HH + n * 16 + lr] = f2bf(o[n][jj]);
    if (lg == 0) {
        const size_t mi = ((size_t)s * BB + b) * TT + jq * 64 + w * 16 + lr;
        mm[mi] = m2;
        ll[mi] = l_run;
    }
}

// ---------------- Kernel 3: merge the four kv-parity partials (bf16 in, fp32 out) ----------------
__global__ __launch_bounds__(256) void attn_merge4(
    const short* __restrict__ opb16, const float* __restrict__ mm,
    const float* __restrict__ ll, float* __restrict__ out)
{
    const int t = blockIdx.x * 256 + threadIdx.x; // 65536
    const int row = t >> 2;
    const int seg = (t & 3) * 16;
    const size_t BT = (size_t)BB * TT;

    float mw[4], lw[4];
#pragma unroll
    for (int w = 0; w < 4; ++w) { mw[w] = mm[w * BT + row]; lw[w] = ll[w * BT + row]; }
    const float M = fmaxf(fmaxf(mw[0], mw[1]), fmaxf(mw[2], mw[3]));
    float ew[4], L = 0.f;
#pragma unroll
    for (int w = 0; w < 4; ++w) { ew[w] = exp2f(mw[w] - M); L += ew[w] * lw[w]; }
    const float inv = 1.f / L;

    float accv[16];
#pragma unroll
    for (int u = 0; u < 16; ++u) accv[u] = 0.f;
#pragma unroll
    for (int w = 0; w < 4; ++w) {
        const short* pb = opb16 + ((w * BT + row) * HH + seg);
        s16x8 v0 = *reinterpret_cast<const s16x8*>(pb);
        s16x8 v1 = *reinterpret_cast<const s16x8*>(pb + 8);
#pragma unroll
        for (int u = 0; u < 8; ++u) {
            accv[u]     += ew[w] * bf2f(v0[u]);
            accv[8 + u] += ew[w] * bf2f(v1[u]);
        }
    }
    float* po = out + (size_t)row * HH + seg;
#pragma unroll
    for (int u = 0; u < 4; ++u) {
        float4 rr = { accv[4 * u] * inv, accv[4 * u + 1] * inv,
                      accv[4 * u + 2] * inv, accv[4 * u + 3] * inv };
        *reinterpret_cast<float4*>(po + 4 * u) = rr;
    }
}

extern "C" void kernel_launch(void* const* d_in, const int* in_sizes, int n_in,
                              void* d_out, int out_size, void* d_ws, size_t ws_size,
                              hipStream_t stream) {
    const float* x  = (const float*)d_in[0];
    const float* Wk = (const float*)d_in[1];
    const float* Wq = (const float*)d_in[2];
    const float* Wv = (const float*)d_in[3];
    float* outp = (float*)d_out;

    const size_t n = (size_t)BB * TT * HH; // 1,048,576
    short* kbuf  = (short*)d_ws;
    short* qbuf  = kbuf + n;
    short* vbuf  = qbuf + n;                // vT layout [B][H][T]
    short* wbf   = vbuf + n;                // 196,608 bf16 weights
    short* opb16 = wbf + 196608;            // [4][B][T][H] bf16 partials (8 MB)
    float* mm    = (float*)(opb16 + 4 * n); // [4][B][T]
    float* ll    = mm + 4 * BB * TT;

    wconv<<<192, 256, 0, stream>>>(Wk, Wq, Wv, wbf);
    proj_fused<<<512, 256, 0, stream>>>(x, wbf, kbuf, qbuf, vbuf);
    attn_split<<<1024, 256, 0, stream>>>(qbuf, kbuf, vbuf, opb16, mm, ll);
    attn_merge4<<<256, 256, 0, stream>>>(opb16, mm, ll, outp);
}

// Round 29
// 46.645 us; speedup vs baseline: 1.1813x; 1.1036x over previous
//
#include <hip/hip_runtime.h>
#include <math.h>

#define BB 8
#define TT 2048
#define CC 1024
#define HH 64
constexpr float SC2 = 0.03125f * 1.4426950408889634f; // (1/sqrt(1024)) * log2(e)

typedef __attribute__((ext_vector_type(8))) short bf16x8;
typedef __attribute__((ext_vector_type(8))) short s16x8;
typedef __attribute__((ext_vector_type(4))) short s16x4;
typedef __attribute__((ext_vector_type(4))) float f32x4;

static __device__ __forceinline__ short f2bf(float f) {
    union { float f; unsigned u; } un; un.f = f;
    unsigned r = un.u + 0x7FFFu + ((un.u >> 16) & 1u); // RNE
    return (short)(r >> 16);
}
static __device__ __forceinline__ float bf2f(short h) {
    union { unsigned u; float f; } un; un.u = ((unsigned)(unsigned short)h) << 16;
    return un.f;
}
static __device__ __forceinline__ bf16x8 cat8(s16x4 lo, s16x4 hi) {
    return __builtin_shufflevector(lo, hi, 0, 1, 2, 3, 4, 5, 6, 7);
}

#define SOFTSYNC() do {                                         \
    asm volatile("s_waitcnt lgkmcnt(0)" ::: "memory");          \
    __builtin_amdgcn_s_barrier();                               \
    __builtin_amdgcn_sched_barrier(0);                          \
  } while (0)

// ---------------- Kernel 0: W -> FRAGMENT-ORDERED bf16 ----------------
// wfrag[wv][ks][kk2][n][lane][8]: lane's B-frag for (col-group wv*48+n*16, k-step ks,
// k-half kk2) is one contiguous 16B load. Same for every proj block (W shared).
__global__ __launch_bounds__(256) void wconv_frag(
    const float* __restrict__ Wk, const float* __restrict__ Wq, const float* __restrict__ Wv,
    short* __restrict__ wfrag)
{
    const int i = blockIdx.x * 256 + threadIdx.x;   // 0..24575
    const int lane = i & 63;
    int g = i >> 6;
    const int n = g % 3;  g /= 3;
    const int kk2 = g & 1; g >>= 1;
    const int ks = g & 15;
    const int wv = g >> 4;                          // 0..3

    const int lr = lane & 15, lg = lane >> 4;
    const int col = wv * 48 + n * 16 + lr;          // 0..191
    const int kb  = ks * 64 + kk2 * 32 + 4 * lg;

    const float* W = (col < 64) ? Wk : (col < 128) ? Wq : Wv;
    const int wr = (col < 64) ? col : (col < 128) ? col - 64 : col - 128;

    float4 lo = *reinterpret_cast<const float4*>(&W[(size_t)wr * CC + kb]);
    float4 hi = *reinterpret_cast<const float4*>(&W[(size_t)wr * CC + kb + 16]);
    s16x8 h = { f2bf(lo.x), f2bf(lo.y), f2bf(lo.z), f2bf(lo.w),
                f2bf(hi.x), f2bf(hi.y), f2bf(hi.z), f2bf(hi.w) };
    *reinterpret_cast<s16x8*>(&wfrag[(size_t)i * 8]) = h;
}

// ---------------- Kernel 1: qkv projection, W frags global->reg (no B LDS) ----------------
// 512 blocks x 32 rows, 2-deep x prefetch, A-only dbuf LDS (9KB).
__global__ __launch_bounds__(256) void proj_fused(
    const float* __restrict__ x, const short* __restrict__ wfrag,
    short* __restrict__ ko, short* __restrict__ qo, short* __restrict__ vT)
{
    __shared__ short At[2][32][72];

    const int tid  = threadIdx.x;
    const int row0 = blockIdx.x * 32;
    const int wv = tid >> 6, lane = tid & 63;
    const int lr = lane & 15, lg = lane >> 4;

    const int ar  = tid >> 4;            // A rows: ar, ar+16
    const int ac4 = (tid & 15) * 4;

    f32x4 acc[2][3] = {};
    float4 axA0, axA1, axB0, axB1;
    s16x8 bw[6];

#define PLA(AX0, AX1, k0_) do {                                                        \
    AX0 = *reinterpret_cast<const float4*>(&x[(size_t)(row0 + ar) * CC + (k0_) + ac4]);       \
    AX1 = *reinterpret_cast<const float4*>(&x[(size_t)(row0 + ar + 16) * CC + (k0_) + ac4]);  \
  } while (0)

#define PWA(bf_, AX0, AX1) do {                                                        \
    s16x4 h0 = { f2bf(AX0.x), f2bf(AX0.y), f2bf(AX0.z), f2bf(AX0.w) };                 \
    s16x4 h1 = { f2bf(AX1.x), f2bf(AX1.y), f2bf(AX1.z), f2bf(AX1.w) };                 \
    *reinterpret_cast<s16x4*>(&At[bf_][ar][ac4]) = h0;                                 \
    *reinterpret_cast<s16x4*>(&At[bf_][ar + 16][ac4]) = h1;                            \
  } while (0)

#define WLOAD(ks_) do {                                                                \
    _Pragma("unroll")                                                                  \
    for (int kk2 = 0; kk2 < 2; ++kk2)                                                  \
        _Pragma("unroll")                                                              \
        for (int n = 0; n < 3; ++n)                                                    \
            bw[kk2 * 3 + n] = *reinterpret_cast<const s16x8*>(                         \
                &wfrag[((((size_t)wv * 16 + (ks_)) * 2 + kk2) * 3 + n) * 512 + lane * 8]); \
  } while (0)

#define PCOMP(bf_) do {                                                                \
    _Pragma("unroll")                                                                  \
    for (int kk2 = 0; kk2 < 2; ++kk2) {                                                \
        bf16x8 aF[2];                                                                  \
        _Pragma("unroll")                                                              \
        for (int m = 0; m < 2; ++m) {                                                  \
            const int row_ = m * 16 + lr;                                              \
            aF[m] = cat8(*reinterpret_cast<const s16x4*>(&At[bf_][row_][kk2 * 32 + 4 * lg]), \
                         *reinterpret_cast<const s16x4*>(&At[bf_][row_][kk2 * 32 + 16 + 4 * lg])); \
        }                                                                              \
        _Pragma("unroll")                                                              \
        for (int m = 0; m < 2; ++m)                                                    \
            _Pragma("unroll")                                                          \
            for (int n = 0; n < 3; ++n)                                                \
                acc[m][n] = __builtin_amdgcn_mfma_f32_16x16x32_bf16(                   \
                    aF[m], *reinterpret_cast<bf16x8*>(&bw[kk2 * 3 + n]), acc[m][n], 0, 0, 0); \
    }                                                                                  \
  } while (0)

    PLA(axA0, axA1, 0);
    PLA(axB0, axB1, 64);
    PWA(0, axA0, axA1);
    SOFTSYNC();

#pragma unroll
    for (int ks = 0; ks < 16; ks += 2) {
        WLOAD(ks);
        if (ks + 2 < 16) PLA(axA0, axA1, (ks + 2) * 64);
        PCOMP(0);
        PWA(1, axB0, axB1);
        SOFTSYNC();
        WLOAD(ks + 1);
        if (ks + 3 < 16) PLA(axB0, axB1, (ks + 3) * 64);
        PCOMP(1);
        if (ks + 2 < 16) PWA(0, axA0, axA1);
        SOFTSYNC();
    }
#undef PLA
#undef PWA
#undef WLOAD
#undef PCOMP

    const int bb = row0 >> 11;
    const int t0 = row0 & 2047;
#pragma unroll
    for (int m = 0; m < 2; ++m)
#pragma unroll
        for (int n = 0; n < 3; ++n) {
            const int col0 = wv * 48 + n * 16;
            const int mat  = col0 >> 6;
            const int hcol = (col0 & 63) + lr;
            const int trow = m * 16 + 4 * lg;
            if (mat == 2) {
                s16x4 pk = { f2bf(acc[m][n][0]), f2bf(acc[m][n][1]),
                             f2bf(acc[m][n][2]), f2bf(acc[m][n][3]) };
                *reinterpret_cast<s16x4*>(&vT[((size_t)bb * HH + hcol) * TT + t0 + trow]) = pk;
            } else {
                short* o = (mat == 0) ? ko : qo;
#pragma unroll
                for (int j = 0; j < 4; ++j)
                    o[(size_t)(row0 + trow + j) * HH + hcol] = f2bf(acc[m][n][j]);
            }
        }
}

// ---------------- Kernel 2: causal flash attention, parity-4 + XCD b-locality + defer-max ----------------
__global__ __launch_bounds__(256) void attn_split(
    const short* __restrict__ q, const short* __restrict__ k,
    const short* __restrict__ vT, short* __restrict__ opb16,
    float* __restrict__ mm, float* __restrict__ ll)
{
    __shared__ short kl[2][4096];  // [kv][h] swizzled
    __shared__ short vl[2][4096];  // [h][t]  swizzled

    const int tid = threadIdx.x;
    const int w = tid >> 6, lane = tid & 63;
    const int lr = lane & 15, lg = lane >> 4;

    const int idx = blockIdx.x;
    const int b = idx & 7;          // XCD-locality: one batch per XCD
    const int j = idx >> 3;
    int jq, s;
    if (j < 64) { jq = j >> 2;              s = j & 3; }
    else        { jq = 31 - ((j - 64) >> 2); s = j & 3; }
    const int cnt = (jq >= s) ? ((jq - s) >> 2) + 1 : 0;

    const short* qb = q  + ((size_t)b * TT + jq * 64 + w * 16) * HH;
    const short* kb = k  + (size_t)b * TT * HH;   // [t][h]
    const short* vb = vT + (size_t)b * HH * TT;   // [h][t]

    bf16x8 aQ[2];
#pragma unroll
    for (int k2 = 0; k2 < 2; ++k2)
        aQ[k2] = cat8(*reinterpret_cast<const s16x4*>(&qb[lr * HH + k2 * 32 + 4 * lg]),
                      *reinterpret_cast<const s16x4*>(&qb[lr * HH + k2 * 32 + 16 + 4 * lg]));

    const int r0 = w * 16 + (lane >> 3);
    const int r1 = r0 + 8;
    const int c7 = lane & 7;
    const int swc = (c7 * 8) ^ ((r0 & 7) << 3);

    f32x4 o[4] = {};
    float m2 = -INFINITY, l_run = 0.f;

    s16x8 sk0, sk1, sv0, sv1;

#define LOADG(t_) do {                                                       \
    const short* kt_ = kb + (size_t)(t_) * 64 * HH;                          \
    const short* vt_ = vb + (t_) * 64;                                       \
    sk0 = *reinterpret_cast<const s16x8*>(&kt_[r0 * HH + c7 * 8]);           \
    sk1 = *reinterpret_cast<const s16x8*>(&kt_[r1 * HH + c7 * 8]);           \
    sv0 = *reinterpret_cast<const s16x8*>(&vt_[(size_t)r0 * TT + c7 * 8]);   \
    sv1 = *reinterpret_cast<const s16x8*>(&vt_[(size_t)r1 * TT + c7 * 8]);   \
  } while (0)

#define WRITELDS(bf_) do {                                                   \
    *reinterpret_cast<s16x8*>(&kl[bf_][r0 * 64 + swc]) = sk0;                \
    *reinterpret_cast<s16x8*>(&kl[bf_][r1 * 64 + swc]) = sk1;                \
    *reinterpret_cast<s16x8*>(&vl[bf_][r0 * 64 + swc]) = sv0;                \
    *reinterpret_cast<s16x8*>(&vl[bf_][r1 * 64 + swc]) = sv1;                \
  } while (0)

    if (cnt > 0) {
        LOADG(s);
        WRITELDS(0);
        SOFTSYNC();

        for (int u = 0; u < cnt; ++u) {
            const int cur = u & 1;
            const int jt = s + 4 * u;
            if (u + 1 < cnt) LOADG(jt + 4);

            f32x4 sv[4] = {};
#pragma unroll
            for (int k2 = 0; k2 < 2; ++k2)
#pragma unroll
                for (int n = 0; n < 4; ++n) {
                    const int row = n * 16 + lr;
                    const int sw = (row & 7) << 3;
                    s16x4 klo = *reinterpret_cast<const s16x4*>(&kl[cur][row * 64 + ((32 * k2 + 4 * lg) ^ sw)]);
                    s16x4 khi = *reinterpret_cast<const s16x4*>(&kl[cur][row * 64 + ((32 * k2 + 4 * lg + 16) ^ sw)]);
                    sv[n] = __builtin_amdgcn_mfma_f32_16x16x32_bf16(cat8(klo, khi), aQ[k2], sv[n], 0, 0, 0);
                }

            if (jt == jq) { // diag tile
#pragma unroll
                for (int n = 0; n < 4; ++n)
#pragma unroll
                    for (int jj = 0; jj < 4; ++jj)
                        if (n * 16 + 4 * lg + jj > w * 16 + lr) sv[n][jj] = -3.0e38f;
            }

            float tm = fmaxf(fmaxf(fmaxf(sv[0][0], sv[0][1]), fmaxf(sv[0][2], sv[0][3])),
                             fmaxf(fmaxf(sv[1][0], sv[1][1]), fmaxf(sv[1][2], sv[1][3])));
            tm = fmaxf(tm, fmaxf(fmaxf(fmaxf(sv[2][0], sv[2][1]), fmaxf(sv[2][2], sv[2][3])),
                                 fmaxf(fmaxf(sv[3][0], sv[3][1]), fmaxf(sv[3][2], sv[3][3]))));
            tm = fmaxf(tm, __shfl_xor(tm, 16));
            tm = fmaxf(tm, __shfl_xor(tm, 32));

            if (!__all((tm * SC2 - m2) <= 8.f)) {   // T13 defer-max
                const float mnew = fmaxf(m2, tm * SC2);
                const float alpha = exp2f(m2 - mnew);
                m2 = mnew;
                l_run *= alpha;
                float alj[4];
#pragma unroll
                for (int jj = 0; jj < 4; ++jj) alj[jj] = __shfl(alpha, 4 * lg + jj);
#pragma unroll
                for (int n = 0; n < 4; ++n)
#pragma unroll
                    for (int jj = 0; jj < 4; ++jj)
                        o[n][jj] *= alj[jj];
            }

            float psum = 0.f;
#pragma unroll
            for (int n = 0; n < 4; ++n)
#pragma unroll
                for (int jj = 0; jj < 4; ++jj) {
                    float p = exp2f(fmaf(sv[n][jj], SC2, -m2));
                    sv[n][jj] = p;
                    psum += p;
                }
            psum += __shfl_xor(psum, 16);
            psum += __shfl_xor(psum, 32);
            l_run += psum;

            bf16x8 aP[2];
#pragma unroll
            for (int k2 = 0; k2 < 2; ++k2) {
                bf16x8 tt;
#pragma unroll
                for (int jj = 0; jj < 4; ++jj) {
                    tt[jj]     = f2bf(sv[2 * k2][jj]);
                    tt[4 + jj] = f2bf(sv[2 * k2 + 1][jj]);
                }
                aP[k2] = tt;
            }
#pragma unroll
            for (int k2 = 0; k2 < 2; ++k2)
#pragma unroll
                for (int n = 0; n < 4; ++n) {
                    const int row = n * 16 + lr;
                    const int sw = (row & 7) << 3;
                    s16x4 vlo = *reinterpret_cast<const s16x4*>(&vl[cur][row * 64 + ((32 * k2 + 4 * lg) ^ sw)]);
                    s16x4 vhi = *reinterpret_cast<const s16x4*>(&vl[cur][row * 64 + ((32 * k2 + 4 * lg + 16) ^ sw)]);
                    o[n] = __builtin_amdgcn_mfma_f32_16x16x32_bf16(aP[k2], cat8(vlo, vhi), o[n], 0, 0, 0);
                }

            if (u + 1 < cnt) WRITELDS(cur ^ 1);
            SOFTSYNC();
        }
    }
#undef LOADG
#undef WRITELDS

    short* opb = opb16 + (((size_t)s * BB + b) * TT + jq * 64 + w * 16) * HH;
#pragma unroll
    for (int n = 0; n < 4; ++n)
#pragma unroll
        for (int jj = 0; jj < 4; ++jj)
            opb[(size_t)(4 * lg + jj) * HH + n * 16 + lr] = f2bf(o[n][jj]);
    if (lg == 0) {
        const size_t mi = ((size_t)s * BB + b) * TT + jq * 64 + w * 16 + lr;
        mm[mi] = m2;
        ll[mi] = l_run;
    }
}

// ---------------- Kernel 3: merge the four kv-parity partials (bf16 in, fp32 out) ----------------
__global__ __launch_bounds__(256) void attn_merge4(
    const short* __restrict__ opb16, const float* __restrict__ mm,
    const float* __restrict__ ll, float* __restrict__ out)
{
    const int t = blockIdx.x * 256 + threadIdx.x; // 65536
    const int row = t >> 2;
    const int seg = (t & 3) * 16;
    const size_t BT = (size_t)BB * TT;

    float mw[4], lw[4];
#pragma unroll
    for (int w = 0; w < 4; ++w) { mw[w] = mm[w * BT + row]; lw[w] = ll[w * BT + row]; }
    const float M = fmaxf(fmaxf(mw[0], mw[1]), fmaxf(mw[2], mw[3]));
    float ew[4], L = 0.f;
#pragma unroll
    for (int w = 0; w < 4; ++w) { ew[w] = exp2f(mw[w] - M); L += ew[w] * lw[w]; }
    const float inv = 1.f / L;

    float accv[16];
#pragma unroll
    for (int u = 0; u < 16; ++u) accv[u] = 0.f;
#pragma unroll
    for (int w = 0; w < 4; ++w) {
        const short* pb = opb16 + ((w * BT + row) * HH + seg);
        s16x8 v0 = *reinterpret_cast<const s16x8*>(pb);
        s16x8 v1 = *reinterpret_cast<const s16x8*>(pb + 8);
#pragma unroll
        for (int u = 0; u < 8; ++u) {
            accv[u]     += ew[w] * bf2f(v0[u]);
            accv[8 + u] += ew[w] * bf2f(v1[u]);
        }
    }
    float* po = out + (size_t)row * HH + seg;
#pragma unroll
    for (int u = 0; u < 4; ++u) {
        float4 rr = { accv[4 * u] * inv, accv[4 * u + 1] * inv,
                      accv[4 * u + 2] * inv, accv[4 * u + 3] * inv };
        *reinterpret_cast<float4*>(po + 4 * u) = rr;
    }
}

extern "C" void kernel_launch(void* const* d_in, const int* in_sizes, int n_in,
                              void* d_out, int out_size, void* d_ws, size_t ws_size,
                              hipStream_t stream) {
    const float* x  = (const float*)d_in[0];
    const float* Wk = (const float*)d_in[1];
    const float* Wq = (const float*)d_in[2];
    const float* Wv = (const float*)d_in[3];
    float* outp = (float*)d_out;

    const size_t n = (size_t)BB * TT * HH; // 1,048,576
    short* kbuf  = (short*)d_ws;
    short* qbuf  = kbuf + n;
    short* vbuf  = qbuf + n;                // vT layout [B][H][T]
    short* wfrag = vbuf + n;                // 196,608 bf16 weights (fragment-ordered)
    short* opb16 = wfrag + 196608;          // [4][B][T][H] bf16 partials (8 MB)
    float* mm    = (float*)(opb16 + 4 * n); // [4][B][T]
    float* ll    = mm + 4 * BB * TT;

    wconv_frag<<<96, 256, 0, stream>>>(Wk, Wq, Wv, wfrag);
    proj_fused<<<512, 256, 0, stream>>>(x, wfrag, kbuf, qbuf, vbuf);
    attn_split<<<1024, 256, 0, stream>>>(qbuf, kbuf, vbuf, opb16, mm, ll);
    attn_merge4<<<256, 256, 0, stream>>>(opb16, mm, ll, outp);
}